// Round 2
// baseline (325.453 us; speedup 1.0000x reference)
//
#include <hip/hip_runtime.h>

typedef _Float16 f16x4 __attribute__((ext_vector_type(4)));
typedef _Float16 f16x8 __attribute__((ext_vector_type(8)));
typedef float    f32x16 __attribute__((ext_vector_type(16)));
typedef float    f32x4v __attribute__((ext_vector_type(4)));

// ---- ws byte offsets (total 8,486,912 B) ----
#define HN_OFF   0u                      // 8192 fp32: 0.5*||e||^2   (32 KB)
#define BEST_OFF 32768u                  // 8192 u64 packed best     (64 KB)
#define ERH_OFF  98304u                  // e-hi, TILED+SWIZZLED     (2 MB)
#define ERL_OFF  (98304u + 2097152u)     // e-lo * 2^11, same layout
#define XRH_OFF  (98304u + 2u * 2097152u) // x-hi, row-major
#define XRL_OFF  (98304u + 3u * 2097152u) // x-lo * 2^11, row-major

// ---- out layout (float indices): [quantized NCHW 1M][encodings 64M] ----
#define OUT_Q    0
#define OUT_ENC  1048576

// e-plane DRAM layout = k2's LDS image: 128 tiles of 64 codes; within a tile,
// f16 elem (w, c) stored at tile*8192 + w*128 + ((c>>3) ^ (w&15))*8 + (c&7).
// Bakes the bank-conflict XOR swizzle into DRAM so global_load_lds can stage
// with a LINEAR wave-uniform destination (rule #21 / m173).

__device__ __forceinline__ void gll16(const void* g, void* l) {
    __builtin_amdgcn_global_load_lds(
        (const __attribute__((address_space(1))) unsigned int*)g,
        (__attribute__((address_space(3))) unsigned int*)l, 16, 0, 0);
}

// K1: split x,e into f16 hi + scaled-lo planes; e-planes written pre-swizzled
// tile-image; fused 0.5*||e||^2; zero-init packed-best array.
__global__ __launch_bounds__(256) void k1_convert(const float* __restrict__ x,
                                                  const float* __restrict__ e,
                                                  char* __restrict__ wsb) {
    int bx = blockIdx.x, tid = threadIdx.x;
    bool is_e = bx < 1024;
    const float* src = is_e ? e : x;
    int sec = is_e ? bx : bx - 1024;
    size_t off = (size_t)sec * 1024 + tid * 4;      // float-element offset
    float4 v = *(const float4*)(src + off);

    f16x4 hi, lo;
    hi[0] = (_Float16)v.x; hi[1] = (_Float16)v.y;
    hi[2] = (_Float16)v.z; hi[3] = (_Float16)v.w;
    lo[0] = (_Float16)((v.x - (float)hi[0]) * 2048.0f);
    lo[1] = (_Float16)((v.y - (float)hi[1]) * 2048.0f);
    lo[2] = (_Float16)((v.z - (float)hi[2]) * 2048.0f);
    lo[3] = (_Float16)((v.w - (float)hi[3]) * 2048.0f);

    if (is_e) {
        int code = (int)(off >> 7);                 // sec*8 + (tid>>5)
        int c = (tid & 31) * 4;
        int tile = code >> 6, w = code & 63;
        int slot = (c >> 3) ^ (w & 15);
        size_t dst = (size_t)tile * 8192 + w * 128 + slot * 8 + (c & 7);
        *(f16x4*)((_Float16*)(wsb + ERH_OFF) + dst) = hi;
        *(f16x4*)((_Float16*)(wsb + ERL_OFF) + dst) = lo;

        float s = v.x * v.x + v.y * v.y + v.z * v.z + v.w * v.w;
        for (int o = 16; o > 0; o >>= 1) s += __shfl_down(s, o, 32);
        if ((tid & 31) == 0)
            ((float*)(wsb + HN_OFF))[code] = 0.5f * s;
    } else {
        _Float16* ph = (_Float16*)(wsb + XRH_OFF);
        _Float16* pl = (_Float16*)(wsb + XRL_OFF);
        *(f16x4*)(ph + off) = hi;
        *(f16x4*)(pl + off) = lo;
        if (sec < 32)
            ((unsigned long long*)(wsb + BEST_OFF))[sec * 256 + tid] = 0ull;
    }
}

// K2: heterogeneous grid, 768 blocks.
//   blocks 0..255   : fill-role — stream-zero 1 MB each of encodings
//                     (plain stores, fill-kernel pattern, no LDS use).
//   blocks 256..767 : MFMA-role — 3-product f16-split argmax over
//                     (128 rows x 1024 codes), T3 minimum 2-phase:
//                     prefetch tile t+1 via global_load_lds, compute tile t,
//                     __syncthreads (drains only the 8 L2-resident glls).
// Both roles co-resident (2 blocks/CU): the 43 us write stream overlaps the
// MFMA stream instead of gating it at 16 barriers per block.
__global__ __launch_bounds__(256, 2) void k2_mfma(char* __restrict__ wsb,
                                                  float* __restrict__ out) {
    __shared__ _Float16 lds_e[2][2][8192];   // [buf][hi/lo][64*128] = 64 KB
    __shared__ float    lds_hn[1024];        // 4 KB

    int bid = blockIdx.x;
    int tid = threadIdx.x;

    if (bid < 256) {
        // ---- fill role: zero 1 MB of encodings, plain coalesced stores ----
        f32x4v z4 = {0.f, 0.f, 0.f, 0.f};
        f32x4v* dst = (f32x4v*)(out + OUT_ENC) + (size_t)bid * 65536 + tid;
        #pragma unroll 8
        for (int i = 0; i < 256; i++)
            dst[i * 256] = z4;
        return;
    }

    const _Float16* xrh = (const _Float16*)(wsb + XRH_OFF);
    const _Float16* xrl = (const _Float16*)(wsb + XRL_OFF);
    const float* hn = (const float*)(wsb + HN_OFF);
    unsigned long long* bestg = (unsigned long long*)(wsb + BEST_OFF);

    int m = bid - 256;
    int bx = m & 63, by = m >> 6;            // consecutive blocks share by -> L2
    int lane = tid & 63, wave = tid >> 6;
    int col = lane & 31, half = lane >> 5;
    int r0 = bx * 128;
    int k0g = by * 1024;
    int row = r0 + wave * 32 + col;          // A-operand m = lane&31

    // A fragments in registers for the whole kernel (row-major x planes)
    f16x8 ah[8], al[8];
    #pragma unroll
    for (int s = 0; s < 8; s++) {
        ah[s] = *(const f16x8*)(xrh + (size_t)row * 128 + s * 16 + half * 8);
        al[s] = *(const f16x8*)(xrl + (size_t)row * 128 + s * 16 + half * 8);
    }

    // stage this chunk's half-norms (1024 fp32)
    *(float4*)(lds_hn + tid * 4) = *(const float4*)(hn + k0g + tid * 4);

    // staging role: wave 0,1 -> hi plane, wave 2,3 -> lo plane; 8 KB each
    int plane = wave >> 1;
    int i0 = (wave & 1) * 8;
    const char* pbase = (const char*)wsb + (plane ? ERL_OFF : ERH_OFF);

    // prologue: stage tile 0 into buf 0 (tile byte base = (k0g + t*64)*256)
    {
        const char* pb = pbase + (size_t)k0g * 256;
        #pragma unroll
        for (int j = 0; j < 8; j++) {
            int idx = i0 + j;
            gll16(pb + idx * 1024 + lane * 16,
                  (char*)&lds_e[0][plane][0] + idx * 1024);
        }
    }
    __syncthreads();                          // tile 0 + hn visible

    float best[16];
    int bidx[16];
    #pragma unroll
    for (int i = 0; i < 16; i++) { best[i] = -3.0e38f; bidx[i] = 0; }

    int b = 0;
    for (int t = 0; t < 16; t++) {
        // (A) issue async prefetch of tile t+1 into buf b^1
        if (t < 15) {
            const char* pb = pbase + (size_t)(k0g + (t + 1) * 64) * 256;
            #pragma unroll
            for (int j = 0; j < 8; j++) {
                int idx = i0 + j;
                gll16(pb + idx * 1024 + lane * 16,
                      (char*)&lds_e[b ^ 1][plane][0] + idx * 1024);
            }
        }

        // (B) compute on buf b (staged last iteration, barrier'd)
        #pragma unroll
        for (int sub = 0; sub < 2; sub++) {
            f32x16 a0, a1, a2;
            #pragma unroll
            for (int i = 0; i < 16; i++) { a0[i] = 0.f; a1[i] = 0.f; a2[i] = 0.f; }
            int cb = (sub * 32 + col) * 128;  // B n-index = lane&31
            #pragma unroll
            for (int s = 0; s < 8; s++) {
                int so = ((s * 2 + half) ^ (col & 15)) * 8;
                f16x8 bh = *(const f16x8*)(&lds_e[b][0][cb + so]);
                f16x8 bl = *(const f16x8*)(&lds_e[b][1][cb + so]);
                a0 = __builtin_amdgcn_mfma_f32_32x32x16_f16(ah[s], bh, a0, 0, 0, 0);
                a1 = __builtin_amdgcn_mfma_f32_32x32x16_f16(ah[s], bl, a1, 0, 0, 0);
                a2 = __builtin_amdgcn_mfma_f32_32x32x16_f16(al[s], bh, a2, 0, 0, 0);
            }
            int code = k0g + t * 64 + sub * 32 + col;
            float hnv = lds_hn[t * 64 + sub * 32 + col];
            #pragma unroll
            for (int r = 0; r < 16; r++) {
                float sc = a0[r] + (a1[r] + a2[r]) * (1.0f / 2048.0f) - hnv;
                if (sc > best[r]) { best[r] = sc; bidx[r] = code; } // > keeps first
            }
        }

        // (C) drain the 8 glls (L2-resident, cheap) + barrier
        __syncthreads();
        b ^= 1;
    }

    // reduce across the 32 cols (same half-wave), then device atomicMax.
    // C/D row = (r&3) + 8*(r>>2) + 4*half ; col = lane&31.
    #pragma unroll
    for (int r = 0; r < 16; r++) {
        float s = best[r];
        int bi = bidx[r];
        #pragma unroll
        for (int mm = 1; mm < 32; mm <<= 1) {
            float qs = __shfl_xor(s, mm, 64);
            int qi = __shfl_xor(bi, mm, 64);
            if (qs > s || (qs == s && qi < bi)) { s = qs; bi = qi; }
        }
        if (col == 0) {
            int rl = (r & 3) + 8 * (r >> 2) + 4 * half;
            unsigned ub = __float_as_uint(s);
            ub = ((int)ub < 0) ? ~ub : (ub | 0x80000000u);   // sortable map
            unsigned long long p = ((unsigned long long)ub << 32) |
                                   (unsigned long long)(0xFFFFFFFFu - (unsigned)bi);
            atomicMax(&bestg[r0 + wave * 32 + rl], p);       // tie -> min idx
        }
    }
}

// K3: decode packed best, write one-hot 1.0, gather e[bi] -> NCHW output.
// 128 blocks: 4-way channel split per n.
__global__ __launch_bounds__(256) void k3_final(const char* __restrict__ wsb,
                                                const float* __restrict__ wgt,
                                                float* __restrict__ out) {
    int bid = blockIdx.x;
    int n = (bid & 31) * 256 + threadIdx.x;   // 0..8191
    int q = bid >> 5;                          // channel quarter 0..3
    unsigned long long p = ((const unsigned long long*)(wsb + BEST_OFF))[n];
    int bi = (int)(0xFFFFFFFFu - (unsigned)(p & 0xFFFFFFFFull));

    if (q == 0)
        out[(size_t)OUT_ENC + (size_t)n * 8192 + bi] = 1.0f;

    // out0[((bq*128 + c)*32 + h)*32 + w], n = bq*1024 + h*32 + w
    int bq = n >> 10, hw = n & 1023;
    float* o = out + (size_t)bq * 131072 + hw + (size_t)q * 32 * 1024;
    const float4* wrow = (const float4*)(wgt + (size_t)bi * 128) + q * 8;
    #pragma unroll
    for (int c4 = 0; c4 < 8; c4++) {
        float4 v = wrow[c4];
        o[(c4 * 4 + 0) * 1024] = v.x;
        o[(c4 * 4 + 1) * 1024] = v.y;
        o[(c4 * 4 + 2) * 1024] = v.z;
        o[(c4 * 4 + 3) * 1024] = v.w;
    }
}

extern "C" void kernel_launch(void* const* d_in, const int* in_sizes, int n_in,
                              void* d_out, int out_size, void* d_ws, size_t ws_size,
                              hipStream_t stream) {
    const float* x = (const float*)d_in[0];   // [8,32,32,128] -> [8192][128]
    const float* e = (const float*)d_in[1];   // [8192][128]
    float* out = (float*)d_out;
    char* ws = (char*)d_ws;

    k1_convert<<<2048, 256, 0, stream>>>(x, e, ws);
    k2_mfma<<<768, 256, 0, stream>>>(ws, out);
    k3_final<<<128, 256, 0, stream>>>(ws, e, out);
}

// Round 3
// 297.256 us; speedup vs baseline: 1.0949x; 1.0949x over previous
//
#include <hip/hip_runtime.h>

typedef _Float16 f16x4 __attribute__((ext_vector_type(4)));
typedef _Float16 f16x8 __attribute__((ext_vector_type(8)));
typedef float    f32x16 __attribute__((ext_vector_type(16)));
typedef float    f32x4v __attribute__((ext_vector_type(4)));

// ---- ws byte offsets (total 8,486,912 B) ----
#define HN_OFF   0u                      // 8192 fp32: 0.5*||e||^2   (32 KB)
#define BEST_OFF 32768u                  // 8192 u64 packed best     (64 KB)
#define ERH_OFF  98304u                  // e-hi, TILED+SWIZZLED     (2 MB)
#define ERL_OFF  (98304u + 2097152u)     // e-lo * 2^11, same layout
#define XRH_OFF  (98304u + 2u * 2097152u) // x-hi, row-major
#define XRL_OFF  (98304u + 3u * 2097152u) // x-lo * 2^11, row-major

// ---- out layout (float indices): [quantized NCHW 1M][encodings 64M] ----
#define OUT_Q    0
#define OUT_ENC  1048576

// e-plane DRAM layout = k2's LDS image: 128 tiles of 64 codes; within a tile,
// f16 elem (w, c) stored at tile*8192 + w*128 + ((c>>3) ^ (w&15))*8 + (c&7).
// Bakes the bank-conflict XOR swizzle into DRAM so global_load_lds can stage
// with a LINEAR wave-uniform destination (rule #21 / m173).

__device__ __forceinline__ void gll16(const void* g, void* l) {
    __builtin_amdgcn_global_load_lds(
        (const __attribute__((address_space(1))) unsigned int*)g,
        (__attribute__((address_space(3))) unsigned int*)l, 16, 0, 0);
}

// K1: split x,e into f16 hi + scaled-lo planes; e-planes written pre-swizzled
// tile-image; fused 0.5*||e||^2; zero-init packed-best array.
__global__ __launch_bounds__(256) void k1_convert(const float* __restrict__ x,
                                                  const float* __restrict__ e,
                                                  char* __restrict__ wsb) {
    int bx = blockIdx.x, tid = threadIdx.x;
    bool is_e = bx < 1024;
    const float* src = is_e ? e : x;
    int sec = is_e ? bx : bx - 1024;
    size_t off = (size_t)sec * 1024 + tid * 4;      // float-element offset
    float4 v = *(const float4*)(src + off);

    f16x4 hi, lo;
    hi[0] = (_Float16)v.x; hi[1] = (_Float16)v.y;
    hi[2] = (_Float16)v.z; hi[3] = (_Float16)v.w;
    lo[0] = (_Float16)((v.x - (float)hi[0]) * 2048.0f);
    lo[1] = (_Float16)((v.y - (float)hi[1]) * 2048.0f);
    lo[2] = (_Float16)((v.z - (float)hi[2]) * 2048.0f);
    lo[3] = (_Float16)((v.w - (float)hi[3]) * 2048.0f);

    if (is_e) {
        int code = (int)(off >> 7);                 // sec*8 + (tid>>5)
        int c = (tid & 31) * 4;
        int tile = code >> 6, w = code & 63;
        int slot = (c >> 3) ^ (w & 15);
        size_t dst = (size_t)tile * 8192 + w * 128 + slot * 8 + (c & 7);
        *(f16x4*)((_Float16*)(wsb + ERH_OFF) + dst) = hi;
        *(f16x4*)((_Float16*)(wsb + ERL_OFF) + dst) = lo;

        float s = v.x * v.x + v.y * v.y + v.z * v.z + v.w * v.w;
        for (int o = 16; o > 0; o >>= 1) s += __shfl_down(s, o, 32);
        if ((tid & 31) == 0)
            ((float*)(wsb + HN_OFF))[code] = 0.5f * s;
    } else {
        _Float16* ph = (_Float16*)(wsb + XRH_OFF);
        _Float16* pl = (_Float16*)(wsb + XRL_OFF);
        *(f16x4*)(ph + off) = hi;
        *(f16x4*)(pl + off) = lo;
        if (sec < 32)
            ((unsigned long long*)(wsb + BEST_OFF))[sec * 256 + tid] = 0ull;
    }
}

// K2: round-1 structure (512 blocks, fused NT enc-fill, counted vmcnt(8))
// + XCD-pinned chunk mapping: by = bid & 7 so each XCD (bid%8 round-robin)
// touches exactly ONE 512-KB e-chunk -> L2-resident reads (T1 mechanism).
__global__ __launch_bounds__(256, 2) void k2_mfma(char* __restrict__ wsb,
                                                  float* __restrict__ out) {
    __shared__ _Float16 lds_e[2][2][8192];   // [buf][hi/lo][64*128] = 64 KB
    __shared__ float    lds_hn[1024];        // 4 KB

    const _Float16* xrh = (const _Float16*)(wsb + XRH_OFF);
    const _Float16* xrl = (const _Float16*)(wsb + XRL_OFF);
    const float* hn = (const float*)(wsb + HN_OFF);
    unsigned long long* bestg = (unsigned long long*)(wsb + BEST_OFF);

    int tid = threadIdx.x;
    int lane = tid & 63, wave = tid >> 6;
    int col = lane & 31, half = lane >> 5;
    int m = blockIdx.x;
    int by = m & 7, bx = m >> 3;             // XCD-pin: same-XCD blocks share by
    int r0 = bx * 128;
    int k0g = by * 1024;
    int row = r0 + wave * 32 + col;          // A-operand m = lane&31

    // A fragments in registers for the whole kernel (row-major x planes)
    f16x8 ah[8], al[8];
    #pragma unroll
    for (int s = 0; s < 8; s++) {
        ah[s] = *(const f16x8*)(xrh + (size_t)row * 128 + s * 16 + half * 8);
        al[s] = *(const f16x8*)(xrl + (size_t)row * 128 + s * 16 + half * 8);
    }

    // stage this chunk's half-norms (1024 fp32)
    *(float4*)(lds_hn + tid * 4) = *(const float4*)(hn + k0g + tid * 4);

    // staging role: wave 0,1 -> hi plane, wave 2,3 -> lo plane; 8 KB each
    int plane = wave >> 1;
    int i0 = (wave & 1) * 8;
    const char* pbase = (const char*)wsb + (plane ? ERL_OFF : ERH_OFF);

    // prologue: stage tile 0 into buf 0 (tile byte base = (k0g + t*64)*256)
    {
        const char* pb = pbase + (size_t)k0g * 256;
        #pragma unroll
        for (int j = 0; j < 8; j++) {
            int idx = i0 + j;
            gll16(pb + idx * 1024 + lane * 16,
                  (char*)&lds_e[0][plane][0] + idx * 1024);
        }
    }
    __syncthreads();                          // full drain once; hn visible

    float best[16];
    int bidx[16];
    #pragma unroll
    for (int i = 0; i < 16; i++) { best[i] = -3.0e38f; bidx[i] = 0; }

    float* encf = out + OUT_ENC;
    long zb4 = (long)(by * 64 + bx) * 32768;  // this block's zero region (f4)
    f32x4v z4 = {0.f, 0.f, 0.f, 0.f};

    int b = 0;
    for (int t = 0; t < 16; t++) {
        // (A) issue async prefetch of tile t+1 into buf b^1
        if (t < 15) {
            const char* pb = pbase + (size_t)(k0g + (t + 1) * 64) * 256;
            #pragma unroll
            for (int j = 0; j < 8; j++) {
                int idx = i0 + j;
                gll16(pb + idx * 1024 + lane * 16,
                      (char*)&lds_e[b ^ 1][plane][0] + idx * 1024);
            }
        }
        asm volatile("" ::: "memory");        // ledger: gll BEFORE stores
        // (B) fused zero-fill slice of encodings (nontemporal, 8x16B/thread;
        //     NT keeps the 512-KB e-chunk L2-resident)
        #pragma unroll
        for (int i = 0; i < 8; i++)
            __builtin_nontemporal_store(
                z4, (f32x4v*)encf + zb4 + t * 2048 + i * 256 + tid);

        // (C) compute on buf b (staged last iteration, barrier'd)
        #pragma unroll
        for (int sub = 0; sub < 2; sub++) {
            f32x16 a0, a1, a2;
            #pragma unroll
            for (int i = 0; i < 16; i++) { a0[i] = 0.f; a1[i] = 0.f; a2[i] = 0.f; }
            int cb = (sub * 32 + col) * 128;  // B n-index = lane&31
            #pragma unroll
            for (int s = 0; s < 8; s++) {
                int so = ((s * 2 + half) ^ (col & 15)) * 8;
                f16x8 bh = *(const f16x8*)(&lds_e[b][0][cb + so]);
                f16x8 bl = *(const f16x8*)(&lds_e[b][1][cb + so]);
                a0 = __builtin_amdgcn_mfma_f32_32x32x16_f16(ah[s], bh, a0, 0, 0, 0);
                a1 = __builtin_amdgcn_mfma_f32_32x32x16_f16(ah[s], bl, a1, 0, 0, 0);
                a2 = __builtin_amdgcn_mfma_f32_32x32x16_f16(al[s], bh, a2, 0, 0, 0);
            }
            int code = k0g + t * 64 + sub * 32 + col;
            float hnv = lds_hn[t * 64 + sub * 32 + col];
            #pragma unroll
            for (int r = 0; r < 16; r++) {
                float sc = a0[r] + (a1[r] + a2[r]) * (1.0f / 2048.0f) - hnv;
                if (sc > best[r]) { best[r] = sc; bidx[r] = code; } // > keeps first
            }
        }

        // (D) counted wait: newest 8 outstanding = this tile's enc stores;
        // everything older (incl. prefetch gll of t+1) must be complete.
        asm volatile("s_waitcnt vmcnt(8)" ::: "memory");
        __builtin_amdgcn_s_barrier();
        b ^= 1;
    }

    // reduce across the 32 cols (same half-wave), then device atomicMax.
    // C/D row = (r&3) + 8*(r>>2) + 4*half ; col = lane&31.
    #pragma unroll
    for (int r = 0; r < 16; r++) {
        float s = best[r];
        int bi = bidx[r];
        #pragma unroll
        for (int mm = 1; mm < 32; mm <<= 1) {
            float qs = __shfl_xor(s, mm, 64);
            int qi = __shfl_xor(bi, mm, 64);
            if (qs > s || (qs == s && qi < bi)) { s = qs; bi = qi; }
        }
        if (col == 0) {
            int rl = (r & 3) + 8 * (r >> 2) + 4 * half;
            unsigned ub = __float_as_uint(s);
            ub = ((int)ub < 0) ? ~ub : (ub | 0x80000000u);   // sortable map
            unsigned long long p = ((unsigned long long)ub << 32) |
                                   (unsigned long long)(0xFFFFFFFFu - (unsigned)bi);
            atomicMax(&bestg[r0 + wave * 32 + rl], p);       // tie -> min idx
        }
    }
}

// K3: decode packed best, write one-hot 1.0, gather e[bi] -> NCHW output.
// 128 blocks: 4-way channel split per n.
__global__ __launch_bounds__(256) void k3_final(const char* __restrict__ wsb,
                                                const float* __restrict__ wgt,
                                                float* __restrict__ out) {
    int bid = blockIdx.x;
    int n = (bid & 31) * 256 + threadIdx.x;   // 0..8191
    int q = bid >> 5;                          // channel quarter 0..3
    unsigned long long p = ((const unsigned long long*)(wsb + BEST_OFF))[n];
    int bi = (int)(0xFFFFFFFFu - (unsigned)(p & 0xFFFFFFFFull));

    if (q == 0)
        out[(size_t)OUT_ENC + (size_t)n * 8192 + bi] = 1.0f;

    // out0[((bq*128 + c)*32 + h)*32 + w], n = bq*1024 + h*32 + w
    int bq = n >> 10, hw = n & 1023;
    float* o = out + (size_t)bq * 131072 + hw + (size_t)q * 32 * 1024;
    const float4* wrow = (const float4*)(wgt + (size_t)bi * 128) + q * 8;
    #pragma unroll
    for (int c4 = 0; c4 < 8; c4++) {
        float4 v = wrow[c4];
        o[(c4 * 4 + 0) * 1024] = v.x;
        o[(c4 * 4 + 1) * 1024] = v.y;
        o[(c4 * 4 + 2) * 1024] = v.z;
        o[(c4 * 4 + 3) * 1024] = v.w;
    }
}

extern "C" void kernel_launch(void* const* d_in, const int* in_sizes, int n_in,
                              void* d_out, int out_size, void* d_ws, size_t ws_size,
                              hipStream_t stream) {
    const float* x = (const float*)d_in[0];   // [8,32,32,128] -> [8192][128]
    const float* e = (const float*)d_in[1];   // [8192][128]
    float* out = (float*)d_out;
    char* ws = (char*)d_ws;

    k1_convert<<<2048, 256, 0, stream>>>(x, e, ws);
    k2_mfma<<<512, 256, 0, stream>>>(ws, out);
    k3_final<<<128, 256, 0, stream>>>(ws, e, out);
}